// Round 10
// baseline (33.818 us; speedup 1.0000x reference)
//
#include <hip/hip_runtime.h>

#define MM 16      // mixtures
#define DD 128     // visible dims
#define CC 50      // categories
#define BB 32768   // batch
#define NP 64      // d-pairs (DD/2)
#define CP 2500    // CC*CC combined categories

// ---------------------------------------------------------------------------
// prep_pairs (round-5 proven structure; only the output pack changed to bf16):
// grid = 64 d01 x 4 quarters. Phase 1: wave-parallel softmax of the 32
// (dloc,m) rows -> LDS bf16. Phase 2: emit bf16 pair entries
// ptab[d01][c0*50+c1][m] = lp[0][c0][m] + lp[1][c1][m], 32B coalesced stores.
// ---------------------------------------------------------------------------
__global__ __launch_bounds__(256) void prep_pairs(
    const float* __restrict__ cate,   // [M][D][C] f32
    unsigned int* __restrict__ ptab)  // [NP][CP][8] u32 (bf16 pairs)
{
    __shared__ unsigned short lp[2][CC][MM];   // 3200 B

    const int tid  = threadIdx.x;
    const int d01  = blockIdx.x >> 2;
    const int q    = blockIdx.x & 3;
    const int wv   = tid >> 6;
    const int lane = tid & 63;

    #pragma unroll
    for (int i = 0; i < 8; ++i) {
        int rr   = wv * 8 + i;        // 0..31
        int dloc = rr >> 4;
        int m    = rr & 15;
        const float* row = cate + (m * DD + 2 * d01 + dloc) * CC;
        float v = (lane < CC) ? row[lane] : -1e30f;

        float mx = v;
        #pragma unroll
        for (int off = 32; off; off >>= 1)
            mx = fmaxf(mx, __shfl_xor(mx, off, 64));
        float e = (lane < CC) ? __expf(v - mx) : 0.f;
        #pragma unroll
        for (int off = 32; off; off >>= 1)
            e += __shfl_xor(e, off, 64);
        float lse = mx + __logf(e);

        if (lane < CC) {
            unsigned int bits = __float_as_uint(v - lse);
            bits += 0x7fffu + ((bits >> 16) & 1u);   // RNE to bf16
            lp[dloc][lane][m] = (unsigned short)(bits >> 16);
        }
    }
    __syncthreads();

    const int e_end = q * 625 + 625;
    for (int e = q * 625 + tid; e < e_end; e += 256) {
        int c0 = e / 50;
        int c1 = e - c0 * 50;
        const uint4* r0 = (const uint4*)&lp[0][c0][0];   // 16 bf16 = 32 B
        const uint4* r1 = (const uint4*)&lp[1][c1][0];
        uint4 A0 = r0[0], A1 = r0[1];
        uint4 B0 = r1[0], B1 = r1[1];
        unsigned int Aw[8] = {A0.x, A0.y, A0.z, A0.w, A1.x, A1.y, A1.z, A1.w};
        unsigned int Bw[8] = {B0.x, B0.y, B0.z, B0.w, B1.x, B1.y, B1.z, B1.w};
        unsigned int P[8];
        #pragma unroll
        for (int w = 0; w < 8; ++w) {
            float lo = __uint_as_float(Aw[w] << 16)
                     + __uint_as_float(Bw[w] << 16);
            float hi = __uint_as_float(Aw[w] & 0xffff0000u)
                     + __uint_as_float(Bw[w] & 0xffff0000u);
            unsigned int b0 = __float_as_uint(lo);
            b0 += 0x7fffu + ((b0 >> 16) & 1u);       // RNE bf16
            unsigned int b1 = __float_as_uint(hi);
            b1 += 0x7fffu + ((b1 >> 16) & 1u);
            P[w] = (b0 >> 16) | (b1 & 0xffff0000u);  // lo = m=2w, hi = m=2w+1
        }
        uint4* dst = (uint4*)(ptab + (size_t)(d01 * CP + e) * 8);
        dst[0] = make_uint4(P[0], P[1], P[2], P[3]);
        dst[1] = make_uint4(P[4], P[5], P[6], P[7]);
    }
}

// ---------------------------------------------------------------------------
// gather_pairs: 32 rows per 256-thread block, grid 1024 (4 blocks/CU,
// 16 waves/CU — 2x r5's occupancy for L3-latency MLP).
// Stage x slab (16 KB) into LDS via nontemporal coalesced loads (x used once;
// nt keeps it from evicting the 5.12MB table out of L2).
// Thread (l = tid&3, half = bit2, r = tid>>3): row b = blk*32+r; lane quad
// reads one 32B entry per d01 as uint2 (m=4l..4l+3, bf16 pairs); halves of
// d01-space combined via shfl_xor(4); quad logsumexp epilogue (r5-proven).
// ---------------------------------------------------------------------------
__global__ __launch_bounds__(256) void gather_pairs(
    const int* __restrict__ x,        // [B][D] int32
    const uint2* __restrict__ tp,     // [NP][CP][4] uint2 (bf16 pairs)
    const float* __restrict__ mw,     // [M]
    float* __restrict__ out)          // [B]
{
    __shared__ int xs[32][132];       // 32 rows x 128 ints, pad 4 (16.9 KB)

    const int tid = threadIdx.x;

    // ---- stage x slab: 2048 x 8B, coalesced, nontemporal ----
    {
        const long long* xg = (const long long*)(x + (size_t)blockIdx.x * 32 * DD);
        #pragma unroll
        for (int k = 0; k < 8; ++k) {
            int i   = k * 256 + tid;  // 0..2047
            int row = i >> 6;         // 64 longlongs per 128-int row
            int col = i & 63;
            long long v = __builtin_nontemporal_load(&xg[i]);
            *(long long*)&xs[row][col * 2] = v;
        }
    }
    __syncthreads();

    const int l    = tid & 3;         // mixture-quad (m = 4l..4l+3)
    const int half = (tid >> 2) & 1;  // d01 half: 0 -> 0..31, 1 -> 32..63
    const int r    = tid >> 3;        // 0..31
    const int b    = blockIdx.x * 32 + r;

    float a0 = 0.f, a1 = 0.f, a2 = 0.f, a3 = 0.f;

    #pragma unroll 8
    for (int j = 0; j < 32; ++j) {
        int d01 = half * 32 + j;
        int2 c2 = *(const int2*)&xs[r][2 * d01];   // ds_read_b64, bank-clean
        int c01 = c2.x * CC + c2.y;
        uint2 u = tp[(d01 * CP + c01) * 4 + l];    // 8B of the 32B entry
        a0 += __uint_as_float(u.x << 16);
        a1 += __uint_as_float(u.x & 0xffff0000u);
        a2 += __uint_as_float(u.y << 16);
        a3 += __uint_as_float(u.y & 0xffff0000u);
    }

    // combine the two d01 halves (lanes differ in tid bit 2)
    a0 += __shfl_xor(a0, 4, 64);
    a1 += __shfl_xor(a1, 4, 64);
    a2 += __shfl_xor(a2, 4, 64);
    a3 += __shfl_xor(a3, 4, 64);

    // uniform log-softmax denominator of mixture weights (r5-proven)
    float mmx = -1e30f;
    #pragma unroll
    for (int k = 0; k < MM; ++k) mmx = fmaxf(mmx, mw[k]);
    float sw = 0.f;
    #pragma unroll
    for (int k = 0; k < MM; ++k) sw += __expf(mw[k] - mmx);
    float lsew = mmx + __logf(sw);

    float l0 = a0 + mw[4 * l + 0] - lsew;
    float l1 = a1 + mw[4 * l + 1] - lsew;
    float l2 = a2 + mw[4 * l + 2] - lsew;
    float l3 = a3 + mw[4 * l + 3] - lsew;

    float mx = fmaxf(fmaxf(l0, l1), fmaxf(l2, l3));
    mx = fmaxf(mx, __shfl_xor(mx, 1, 64));
    mx = fmaxf(mx, __shfl_xor(mx, 2, 64));
    float e = __expf(l0 - mx) + __expf(l1 - mx) + __expf(l2 - mx) + __expf(l3 - mx);
    e += __shfl_xor(e, 1, 64);
    e += __shfl_xor(e, 2, 64);

    if ((tid & 7) == 0) out[b] = mx + __logf(e);
}

extern "C" void kernel_launch(void* const* d_in, const int* in_sizes, int n_in,
                              void* d_out, int out_size, void* d_ws, size_t ws_size,
                              hipStream_t stream) {
    const int*   x    = (const int*)d_in[0];     // [B][D]
    const float* mw   = (const float*)d_in[1];   // [M]
    const float* cate = (const float*)d_in[2];   // [M][D][C]
    float* out = (float*)d_out;

    unsigned int* ptab = (unsigned int*)d_ws;    // NP*CP*8 u32 = 5,120,000 B

    prep_pairs<<<256, 256, 0, stream>>>(cate, ptab);
    gather_pairs<<<BB / 32, 256, 0, stream>>>(x, (const uint2*)ptab, mw, out);
}